// Round 3
// baseline (278.034 us; speedup 1.0000x reference)
//
#include <hip/hip_runtime.h>
#include <hip/hip_cooperative_groups.h>

namespace cg = cooperative_groups;

// ProSurv similarity loss, collapsed:
//   cm[b,c] = (h[b] . bankbar[c]) / max(||h[b]||, eps)
//   bankbar[c] = (1/M) sum_m bank[c,m] / max(||bank[c,m]||, eps)
// Single cooperative kernel, 4 phases separated by grid.sync().

constexpr int NC = 4;     // classes
constexpr int NM = 512;   // prototypes per class
constexpr int ND = 256;   // feature dim
constexpr float EPSF = 1e-12f;

constexpr int NBLK = 512;
constexpr int NTHR = 256;
constexpr int ROWS_TOTAL = 2 * NC * NM;            // 4096 bank rows
constexpr int ROWS_PER_BLOCK = ROWS_TOTAL / NBLK;  // 8
constexpr int SEG = NM / ROWS_PER_BLOCK;           // 64 blocks per (bank,class)

__device__ __forceinline__ float wave_reduce(float v) {
#pragma unroll
    for (int off = 32; off >= 1; off >>= 1)
        v += __shfl_xor(v, off, 64);
    return v;
}

__global__ __launch_bounds__(NTHR) void fused_kernel(
    const float* __restrict__ hp, const float* __restrict__ hg,
    const float* __restrict__ pbank, const float* __restrict__ gbank,
    const int* __restrict__ label, const int* __restrict__ censor,
    float* __restrict__ partials, float* __restrict__ bankbar,
    float* __restrict__ lpart, float* __restrict__ out,
    int samples_per_wave)
{
    cg::grid_group grid = cg::this_grid();
    const int blk  = blockIdx.x;
    const int wave = threadIdx.x >> 6;
    const int lane = threadIdx.x & 63;

    __shared__ float4 red[4][64];        // phase 1 cross-wave combine
    __shared__ float  sb[2 * NC * ND];   // phase 3 bankbar copy (8 KiB)
    __shared__ float  wpart[4];

    // ---- Phase 1: normalized row partial sums (8 rows per block) ----
    {
        float4 acc = {0.f, 0.f, 0.f, 0.f};
#pragma unroll
        for (int rr = 0; rr < 2; ++rr) {
            const int r      = blk * ROWS_PER_BLOCK + wave * 2 + rr;
            const int bank   = r >> 11;
            const int within = r & (NC * NM - 1);
            const float* src = (bank ? gbank : pbank) + (size_t)within * ND;
            const float4 v = reinterpret_cast<const float4*>(src)[lane];
            float ss = v.x * v.x + v.y * v.y + v.z * v.z + v.w * v.w;
            ss = wave_reduce(ss);
            const float inv = 1.0f / (fmaxf(sqrtf(ss), EPSF) * (float)NM);
            acc.x += v.x * inv; acc.y += v.y * inv;
            acc.z += v.z * inv; acc.w += v.w * inv;
        }
        red[wave][lane] = acc;
        __syncthreads();
        if (wave == 0) {
            float4 a = red[0][lane], b = red[1][lane];
            float4 c = red[2][lane], d = red[3][lane];
            a.x += b.x + c.x + d.x; a.y += b.y + c.y + d.y;
            a.z += b.z + c.z + d.z; a.w += b.w + c.w + d.w;
            reinterpret_cast<float4*>(partials + (size_t)blk * ND)[lane] = a;
        }
    }
    __threadfence();
    grid.sync();

    // ---- Phase 2: finalize bankbar; block computes one float4 column ----
    {
        const int combo = blk >> 6;      // 0..7 = bank*NC + class
        const int f4    = blk & 63;      // which float4 of the 64 in a row
        if (wave == 0) {
            const float4 v = reinterpret_cast<const float4*>(
                partials + (size_t)(combo * SEG + lane) * ND)[f4];
            float x = wave_reduce(v.x), y = wave_reduce(v.y);
            float z = wave_reduce(v.z), w = wave_reduce(v.w);
            if (lane == 0) {
                float4 o = {x, y, z, w};
                reinterpret_cast<float4*>(bankbar + (size_t)combo * ND)[f4] = o;
            }
        }
    }
    __threadfence();
    grid.sync();

    // ---- Phase 3: per-sample loss ----
    {
        for (int i = threadIdx.x; i < 2 * NC * ND; i += NTHR)
            sb[i] = bankbar[i];
        __syncthreads();

        const int wid = blk * 4 + wave;
        float contrib = 0.0f;

        for (int i = 0; i < samples_per_wave; ++i) {
            const int b = wid * samples_per_wave + i;
            // both modality vectors up-front (more loads in flight)
            const float4 vp = reinterpret_cast<const float4*>(hp + (size_t)b * ND)[lane];
            const float4 vg = reinterpret_cast<const float4*>(hg + (size_t)b * ND)[lane];
            const int  l   = label[b];
            const bool evt = (censor[b] == 0);

            float s0p = vp.x * vp.x + vp.y * vp.y + vp.z * vp.z + vp.w * vp.w;
            float s0g = vg.x * vg.x + vg.y * vg.y + vg.z * vg.z + vg.w * vg.w;
            float scp[NC], scg[NC];
#pragma unroll
            for (int c = 0; c < NC; ++c) {
                const float4 wp4 = reinterpret_cast<const float4*>(sb + c * ND)[lane];
                const float4 wg4 = reinterpret_cast<const float4*>(sb + (NC + c) * ND)[lane];
                scp[c] = vp.x * wp4.x + vp.y * wp4.y + vp.z * wp4.z + vp.w * wp4.w;
                scg[c] = vg.x * wg4.x + vg.y * wg4.y + vg.z * wg4.z + vg.w * wg4.w;
            }
            // joint 10-value butterfly reduce
#pragma unroll
            for (int off = 32; off >= 1; off >>= 1) {
                s0p += __shfl_xor(s0p, off, 64);
                s0g += __shfl_xor(s0g, off, 64);
#pragma unroll
                for (int c = 0; c < NC; ++c) {
                    scp[c] += __shfl_xor(scp[c], off, 64);
                    scg[c] += __shfl_xor(scg[c], off, 64);
                }
            }
            const float invp = 1.0f / fmaxf(sqrtf(s0p), EPSF);
            const float invg = 1.0f / fmaxf(sqrtf(s0g), EPSF);

#pragma unroll
            for (int md = 0; md < 2; ++md) {
                const float inv = md ? invg : invp;
                float sum = 0.f, cml = 0.f, sge = 0.f, slt = 0.f;
#pragma unroll
                for (int c = 0; c < NC; ++c) {
                    const float x = (md ? scg[c] : scp[c]) * inv;
                    sum += x;
                    if (c == l) cml = x;
                    if (c >= l) sge += x; else slt += x;
                }
                float pos, neg;
                if (evt) {
                    pos = cml;
                    neg = (sum - cml) * (1.0f / (NC - 1));
                } else {
                    pos = sge / (float)(NC - l);          // l==0 -> pos_all
                    neg = slt / (float)(l > 0 ? l : 1);   // l==0 -> 0
                }
                contrib += neg - pos;
            }
        }

        if (lane == 0) wpart[wave] = contrib;
        __syncthreads();
        if (threadIdx.x == 0)
            lpart[blk] = wpart[0] + wpart[1] + wpart[2] + wpart[3];
    }
    __threadfence();
    grid.sync();

    // ---- Phase 4: final reduce (block 0) ----
    if (blk == 0) {
        const int t = threadIdx.x;
        float v = lpart[t] + lpart[t + NTHR];
        v = wave_reduce(v);
        if (lane == 0) wpart[wave] = v;
        __syncthreads();
        if (t == 0) out[0] = wpart[0] + wpart[1] + wpart[2] + wpart[3];
    }
}

extern "C" void kernel_launch(void* const* d_in, const int* in_sizes, int n_in,
                              void* d_out, int out_size, void* d_ws, size_t ws_size,
                              hipStream_t stream)
{
    const float* hp     = (const float*)d_in[0];
    const float* hg     = (const float*)d_in[1];
    const float* pb     = (const float*)d_in[2];
    const float* gb     = (const float*)d_in[3];
    const int*   label  = (const int*)d_in[4];
    const int*   censor = (const int*)d_in[5];
    float*       out    = (float*)d_out;

    float* partials = (float*)d_ws;                           // NBLK*ND = 512 KiB
    float* bankbar  = partials + (size_t)NBLK * ND;           // 8 KiB
    float* lpart    = bankbar + 2 * NC * ND;                  // NBLK floats

    const int B = in_sizes[0] / ND;                           // 16384
    int samples_per_wave = B / (NBLK * 4);                    // 8

    void* args[] = {
        (void*)&hp, (void*)&hg, (void*)&pb, (void*)&gb,
        (void*)&label, (void*)&censor,
        (void*)&partials, (void*)&bankbar, (void*)&lpart, (void*)&out,
        (void*)&samples_per_wave
    };
    hipLaunchCooperativeKernel((const void*)fused_kernel,
                               dim3(NBLK), dim3(NTHR), args, 0, stream);
}

// Round 4
// 81.015 us; speedup vs baseline: 3.4319x; 3.4319x over previous
//
#include <hip/hip_runtime.h>

// ProSurv similarity loss, collapsed:
//   cm[b,c] = (h[b] . bankbar[c]) / max(||h[b]||, eps)
//   bankbar[c] = (1/M) sum_m bank[c,m] / max(||bank[c,m]||, eps)
// 3 dispatches: memset(counters) ; bank_kernel (last-block finalize) ;
// loss_kernel (last-block final reduce). All reductions fixed-order.

constexpr int NC = 4;     // classes
constexpr int NM = 512;   // prototypes per class
constexpr int ND = 256;   // feature dim
constexpr float EPSF = 1e-12f;

constexpr int ABLK = 64;                              // bank_kernel blocks
constexpr int ROWS_PER_ABLK  = 2 * NC * NM / ABLK;    // 64
constexpr int ROWS_PER_AWAVE = ROWS_PER_ABLK / 4;     // 16
constexpr int PART_PER_COMBO = ABLK / (2 * NC);       // 8 partials per (bank,class)

constexpr int BBLK = 2048;                            // loss_kernel blocks
constexpr int SPW  = 2;                               // samples per wave

__device__ __forceinline__ float wave_reduce(float v) {
#pragma unroll
    for (int off = 32; off >= 1; off >>= 1)
        v += __shfl_xor(v, off, 64);
    return v;
}

// ---- Kernel 1: bank partials + last-block finalize -> bankbar ----
__global__ __launch_bounds__(256) void bank_kernel(
    const float* __restrict__ pbank, const float* __restrict__ gbank,
    float* __restrict__ partials, float* __restrict__ bankbar,
    unsigned int* __restrict__ counterA)
{
    const int blk  = blockIdx.x;
    const int wave = threadIdx.x >> 6;
    const int lane = threadIdx.x & 63;

    float4 acc = {0.f, 0.f, 0.f, 0.f};
    const int r0 = blk * ROWS_PER_ABLK + wave * ROWS_PER_AWAVE;
#pragma unroll
    for (int rr = 0; rr < ROWS_PER_AWAVE; ++rr) {
        const int r      = r0 + rr;
        const int bank   = r >> 11;                 // / (NC*NM)
        const int within = r & (NC * NM - 1);
        const float* src = (bank ? gbank : pbank) + (size_t)within * ND;
        const float4 v = reinterpret_cast<const float4*>(src)[lane];
        float ss = v.x * v.x + v.y * v.y + v.z * v.z + v.w * v.w;
        ss = wave_reduce(ss);
        const float inv = 1.0f / (fmaxf(sqrtf(ss), EPSF) * (float)NM);
        acc.x += v.x * inv; acc.y += v.y * inv;
        acc.z += v.z * inv; acc.w += v.w * inv;
    }

    __shared__ float4 red[4][64];
    red[wave][lane] = acc;
    __syncthreads();
    if (wave == 0) {
        float4 a = red[0][lane], b = red[1][lane];
        float4 c = red[2][lane], d = red[3][lane];
        a.x += b.x + c.x + d.x; a.y += b.y + c.y + d.y;
        a.z += b.z + c.z + d.z; a.w += b.w + c.w + d.w;
        reinterpret_cast<float4*>(partials + (size_t)blk * ND)[lane] = a;
    }
    __syncthreads();   // drains wave0's stores (vmcnt) before counter bump

    __shared__ bool last;
    if (threadIdx.x == 0) {
        __threadfence();
        const unsigned int old = atomicAdd(counterA, 1u);
        last = (old == ABLK - 1);
    }
    __syncthreads();

    if (last) {
        __threadfence();   // acquire: see all blocks' partials
        // thread t: combo c = t/32, float4 columns (t%32) and (t%32)+32
        const int c = threadIdx.x >> 5;
        const int j = threadIdx.x & 31;
#pragma unroll
        for (int k = 0; k < 2; ++k) {
            const int f4 = j + k * 32;              // 0..63
            float4 s = {0.f, 0.f, 0.f, 0.f};
#pragma unroll
            for (int p = 0; p < PART_PER_COMBO; ++p) {
                const float4 v = reinterpret_cast<const float4*>(
                    partials + (size_t)(c * PART_PER_COMBO + p) * ND)[f4];
                s.x += v.x; s.y += v.y; s.z += v.z; s.w += v.w;
            }
            reinterpret_cast<float4*>(bankbar + (size_t)c * ND)[f4] = s;
        }
    }
}

// ---- Kernel 2: per-sample loss + last-block final reduce -> out ----
__global__ __launch_bounds__(256) void loss_kernel(
    const float* __restrict__ hp, const float* __restrict__ hg,
    const int* __restrict__ label, const int* __restrict__ censor,
    const float* __restrict__ bankbar, float* __restrict__ lpart,
    float* __restrict__ out, unsigned int* __restrict__ counterB)
{
    __shared__ float sb[2 * NC * ND];   // 8 KiB
    for (int i = threadIdx.x; i < 2 * NC * ND; i += 256)
        sb[i] = bankbar[i];
    __syncthreads();

    const int wave = threadIdx.x >> 6;
    const int lane = threadIdx.x & 63;
    const int wid  = blockIdx.x * 4 + wave;

    float contrib = 0.0f;
#pragma unroll
    for (int i = 0; i < SPW; ++i) {
        const int b = wid * SPW + i;
        const float4 vp = reinterpret_cast<const float4*>(hp + (size_t)b * ND)[lane];
        const float4 vg = reinterpret_cast<const float4*>(hg + (size_t)b * ND)[lane];
        const int  l   = label[b];
        const bool evt = (censor[b] == 0);

        float s0p = vp.x * vp.x + vp.y * vp.y + vp.z * vp.z + vp.w * vp.w;
        float s0g = vg.x * vg.x + vg.y * vg.y + vg.z * vg.z + vg.w * vg.w;
        float scp[NC], scg[NC];
#pragma unroll
        for (int c = 0; c < NC; ++c) {
            const float4 wp4 = reinterpret_cast<const float4*>(sb + c * ND)[lane];
            const float4 wg4 = reinterpret_cast<const float4*>(sb + (NC + c) * ND)[lane];
            scp[c] = vp.x * wp4.x + vp.y * wp4.y + vp.z * wp4.z + vp.w * wp4.w;
            scg[c] = vg.x * wg4.x + vg.y * wg4.y + vg.z * wg4.z + vg.w * wg4.w;
        }
#pragma unroll
        for (int off = 32; off >= 1; off >>= 1) {
            s0p += __shfl_xor(s0p, off, 64);
            s0g += __shfl_xor(s0g, off, 64);
#pragma unroll
            for (int c = 0; c < NC; ++c) {
                scp[c] += __shfl_xor(scp[c], off, 64);
                scg[c] += __shfl_xor(scg[c], off, 64);
            }
        }
        const float invp = 1.0f / fmaxf(sqrtf(s0p), EPSF);
        const float invg = 1.0f / fmaxf(sqrtf(s0g), EPSF);

#pragma unroll
        for (int md = 0; md < 2; ++md) {
            const float inv = md ? invg : invp;
            float sum = 0.f, cml = 0.f, sge = 0.f, slt = 0.f;
#pragma unroll
            for (int c = 0; c < NC; ++c) {
                const float x = (md ? scg[c] : scp[c]) * inv;
                sum += x;
                if (c == l) cml = x;
                if (c >= l) sge += x; else slt += x;
            }
            float pos, neg;
            if (evt) {
                pos = cml;
                neg = (sum - cml) * (1.0f / (NC - 1));
            } else {
                pos = sge / (float)(NC - l);          // l==0 -> pos_all
                neg = slt / (float)(l > 0 ? l : 1);   // l==0 -> 0
            }
            contrib += neg - pos;
        }
    }

    __shared__ float wpart[4];
    if (lane == 0) wpart[wave] = contrib;
    __syncthreads();

    __shared__ bool last;
    if (threadIdx.x == 0) {
        lpart[blockIdx.x] = wpart[0] + wpart[1] + wpart[2] + wpart[3];
        __threadfence();   // same thread stored lpart: program-order release
        const unsigned int old = atomicAdd(counterB, 1u);
        last = (old == BBLK - 1);
    }
    __syncthreads();

    if (last) {
        __threadfence();   // acquire: see all blocks' lpart
        const int t = threadIdx.x;
        float v = 0.f;
#pragma unroll
        for (int k = 0; k < BBLK / 256; ++k)
            v += lpart[t + k * 256];
        v = wave_reduce(v);
        __shared__ float wp2[4];
        if (lane == 0) wp2[wave] = v;
        __syncthreads();
        if (t == 0) out[0] = wp2[0] + wp2[1] + wp2[2] + wp2[3];
    }
}

extern "C" void kernel_launch(void* const* d_in, const int* in_sizes, int n_in,
                              void* d_out, int out_size, void* d_ws, size_t ws_size,
                              hipStream_t stream)
{
    const float* hp     = (const float*)d_in[0];
    const float* hg     = (const float*)d_in[1];
    const float* pb     = (const float*)d_in[2];
    const float* gb     = (const float*)d_in[3];
    const int*   label  = (const int*)d_in[4];
    const int*   censor = (const int*)d_in[5];
    float*       out    = (float*)d_out;

    unsigned int* counters = (unsigned int*)d_ws;             // [0]=A, [1]=B
    float* partials = (float*)((char*)d_ws + 16);             // ABLK*ND = 64 KiB
    float* bankbar  = partials + (size_t)ABLK * ND;           // 8 KiB
    float* lpart    = bankbar + 2 * NC * ND;                  // BBLK floats

    hipMemsetAsync(counters, 0, 16, stream);
    bank_kernel<<<ABLK, 256, 0, stream>>>(pb, gb, partials, bankbar,
                                          counters + 0);
    loss_kernel<<<BBLK, 256, 0, stream>>>(hp, hg, label, censor,
                                          bankbar, lpart, out, counters + 1);
}

// Round 5
// 47.664 us; speedup vs baseline: 5.8332x; 1.6997x over previous
//
#include <hip/hip_runtime.h>

// ProSurv similarity loss, collapsed:
//   cm[b,c] = (h[b] . bankbar[c]) / max(||h[b]||, eps)
//   bankbar[c] = (1/M) sum_m bank[c,m] / max(||bank[c,m]||, eps)
// 4 dispatches, all fence-free; cross-kernel visibility via dispatch
// boundaries only. Final sum via one float atomicAdd per loss block
// (out zeroed by a 4-byte memset each launch).

constexpr int NC = 4;     // classes
constexpr int NM = 512;   // prototypes per class
constexpr int ND = 256;   // feature dim
constexpr float EPSF = 1e-12f;

constexpr int ABLK = 128;                             // bank_partial blocks
constexpr int ROWS_PER_ABLK  = 2 * NC * NM / ABLK;    // 32
constexpr int ROWS_PER_AWAVE = ROWS_PER_ABLK / 4;     // 8
constexpr int PART_PER_COMBO = ABLK / (2 * NC);       // 16

constexpr int BBLK = 2048;                            // loss blocks
constexpr int SPW  = 2;                               // samples per wave

__device__ __forceinline__ float wave_reduce(float v) {
#pragma unroll
    for (int off = 32; off >= 1; off >>= 1)
        v += __shfl_xor(v, off, 64);
    return v;
}

// ---- Kernel 1: normalized-row partial sums (32 rows per block) ----
__global__ __launch_bounds__(256) void bank_partial_kernel(
    const float* __restrict__ pbank, const float* __restrict__ gbank,
    float* __restrict__ partials)
{
    const int blk  = blockIdx.x;
    const int wave = threadIdx.x >> 6;
    const int lane = threadIdx.x & 63;

    float4 acc = {0.f, 0.f, 0.f, 0.f};
    const int r0 = blk * ROWS_PER_ABLK + wave * ROWS_PER_AWAVE;
#pragma unroll
    for (int rr = 0; rr < ROWS_PER_AWAVE; ++rr) {
        const int r      = r0 + rr;
        const int bank   = r >> 11;                 // / (NC*NM)
        const int within = r & (NC * NM - 1);
        const float* src = (bank ? gbank : pbank) + (size_t)within * ND;
        const float4 v = reinterpret_cast<const float4*>(src)[lane];
        float ss = v.x * v.x + v.y * v.y + v.z * v.z + v.w * v.w;
        ss = wave_reduce(ss);
        const float inv = 1.0f / (fmaxf(sqrtf(ss), EPSF) * (float)NM);
        acc.x += v.x * inv; acc.y += v.y * inv;
        acc.z += v.z * inv; acc.w += v.w * inv;
    }

    __shared__ float4 red[4][64];
    red[wave][lane] = acc;
    __syncthreads();
    if (wave == 0) {
        float4 a = red[0][lane], b = red[1][lane];
        float4 c = red[2][lane], d = red[3][lane];
        a.x += b.x + c.x + d.x; a.y += b.y + c.y + d.y;
        a.z += b.z + c.z + d.z; a.w += b.w + c.w + d.w;
        reinterpret_cast<float4*>(partials + (size_t)blk * ND)[lane] = a;
    }
}

// ---- Kernel 2: sum 16 partials per combo -> bankbar (8 blocks) ----
__global__ __launch_bounds__(256) void bank_final_kernel(
    const float* __restrict__ partials, float* __restrict__ bankbar)
{
    const int combo = blockIdx.x;
    const int t     = threadIdx.x;
    float acc = 0.f;
#pragma unroll
    for (int p = 0; p < PART_PER_COMBO; ++p)
        acc += partials[(size_t)(combo * PART_PER_COMBO + p) * ND + t];
    bankbar[(size_t)combo * ND + t] = acc;
}

// ---- Kernel 3: per-sample loss; one atomicAdd(out) per block ----
__global__ __launch_bounds__(256) void loss_kernel(
    const float* __restrict__ hp, const float* __restrict__ hg,
    const int* __restrict__ label, const int* __restrict__ censor,
    const float* __restrict__ bankbar, float* __restrict__ out)
{
    __shared__ float sb[2 * NC * ND];   // 8 KiB
    for (int i = threadIdx.x; i < 2 * NC * ND; i += 256)
        sb[i] = bankbar[i];
    __syncthreads();

    const int wave = threadIdx.x >> 6;
    const int lane = threadIdx.x & 63;
    const int wid  = blockIdx.x * 4 + wave;

    float contrib = 0.0f;
#pragma unroll
    for (int i = 0; i < SPW; ++i) {
        const int b = wid * SPW + i;
        const float4 vp = reinterpret_cast<const float4*>(hp + (size_t)b * ND)[lane];
        const float4 vg = reinterpret_cast<const float4*>(hg + (size_t)b * ND)[lane];
        const int  l   = label[b];
        const bool evt = (censor[b] == 0);

        float s0p = vp.x * vp.x + vp.y * vp.y + vp.z * vp.z + vp.w * vp.w;
        float s0g = vg.x * vg.x + vg.y * vg.y + vg.z * vg.z + vg.w * vg.w;
        float scp[NC], scg[NC];
#pragma unroll
        for (int c = 0; c < NC; ++c) {
            const float4 wp4 = reinterpret_cast<const float4*>(sb + c * ND)[lane];
            const float4 wg4 = reinterpret_cast<const float4*>(sb + (NC + c) * ND)[lane];
            scp[c] = vp.x * wp4.x + vp.y * wp4.y + vp.z * wp4.z + vp.w * wp4.w;
            scg[c] = vg.x * wg4.x + vg.y * wg4.y + vg.z * wg4.z + vg.w * wg4.w;
        }
#pragma unroll
        for (int off = 32; off >= 1; off >>= 1) {
            s0p += __shfl_xor(s0p, off, 64);
            s0g += __shfl_xor(s0g, off, 64);
#pragma unroll
            for (int c = 0; c < NC; ++c) {
                scp[c] += __shfl_xor(scp[c], off, 64);
                scg[c] += __shfl_xor(scg[c], off, 64);
            }
        }
        const float invp = 1.0f / fmaxf(sqrtf(s0p), EPSF);
        const float invg = 1.0f / fmaxf(sqrtf(s0g), EPSF);

#pragma unroll
        for (int md = 0; md < 2; ++md) {
            const float inv = md ? invg : invp;
            float sum = 0.f, cml = 0.f, sge = 0.f, slt = 0.f;
#pragma unroll
            for (int c = 0; c < NC; ++c) {
                const float x = (md ? scg[c] : scp[c]) * inv;
                sum += x;
                if (c == l) cml = x;
                if (c >= l) sge += x; else slt += x;
            }
            float pos, neg;
            if (evt) {
                pos = cml;
                neg = (sum - cml) * (1.0f / (NC - 1));
            } else {
                pos = sge / (float)(NC - l);          // l==0 -> pos_all
                neg = slt / (float)(l > 0 ? l : 1);   // l==0 -> 0
            }
            contrib += neg - pos;
        }
    }

    __shared__ float wpart[4];
    if (lane == 0) wpart[wave] = contrib;
    __syncthreads();
    if (threadIdx.x == 0)
        atomicAdd(out, wpart[0] + wpart[1] + wpart[2] + wpart[3]);
}

extern "C" void kernel_launch(void* const* d_in, const int* in_sizes, int n_in,
                              void* d_out, int out_size, void* d_ws, size_t ws_size,
                              hipStream_t stream)
{
    const float* hp     = (const float*)d_in[0];
    const float* hg     = (const float*)d_in[1];
    const float* pb     = (const float*)d_in[2];
    const float* gb     = (const float*)d_in[3];
    const int*   label  = (const int*)d_in[4];
    const int*   censor = (const int*)d_in[5];
    float*       out    = (float*)d_out;

    float* partials = (float*)d_ws;                           // ABLK*ND = 128 KiB
    float* bankbar  = partials + (size_t)ABLK * ND;           // 8 KiB

    hipMemsetAsync(out, 0, sizeof(float), stream);
    bank_partial_kernel<<<ABLK, 256, 0, stream>>>(pb, gb, partials);
    bank_final_kernel  <<<2 * NC, 256, 0, stream>>>(partials, bankbar);
    loss_kernel        <<<BBLK, 256, 0, stream>>>(hp, hg, label, censor,
                                                  bankbar, out);
}

// Round 6
// 43.449 us; speedup vs baseline: 6.3991x; 1.0970x over previous
//
#include <hip/hip_runtime.h>

// ProSurv similarity loss, collapsed:
//   cm[b,c] = (h[b] . bankbar[c]) / max(||h[b]||, eps)
//   bankbar[c] = (1/M) sum_m bank[c,m] / max(||bank[c,m]||, eps)
// 3 dispatches, fence-free, no memsets: out is zeroed by kernel 1 (block 0),
// consumed by kernel 3 two dispatch-boundaries later. Final sum via one
// float atomicAdd per loss block.

constexpr int NC = 4;     // classes
constexpr int NM = 512;   // prototypes per class
constexpr int ND = 256;   // feature dim
constexpr float EPSF = 1e-12f;

constexpr int ABLK = 128;                             // bank_partial blocks
constexpr int ROWS_PER_ABLK  = 2 * NC * NM / ABLK;    // 32
constexpr int ROWS_PER_AWAVE = ROWS_PER_ABLK / 4;     // 8
constexpr int PART_PER_COMBO = ABLK / (2 * NC);       // 16

constexpr int BBLK = 2048;                            // loss blocks
constexpr int SPW  = 2;                               // samples per wave

__device__ __forceinline__ float wave_reduce(float v) {
#pragma unroll
    for (int off = 32; off >= 1; off >>= 1)
        v += __shfl_xor(v, off, 64);
    return v;
}

// ---- Kernel 1: normalized-row partial sums (32 rows per block) ----
//      Also zeroes out[0] (visible to kernel 3 across dispatch boundaries).
__global__ __launch_bounds__(256) void bank_partial_kernel(
    const float* __restrict__ pbank, const float* __restrict__ gbank,
    float* __restrict__ partials, float* __restrict__ out)
{
    if (blockIdx.x == 0 && threadIdx.x == 0)
        out[0] = 0.0f;

    const int blk  = blockIdx.x;
    const int wave = threadIdx.x >> 6;
    const int lane = threadIdx.x & 63;

    float4 acc = {0.f, 0.f, 0.f, 0.f};
    const int r0 = blk * ROWS_PER_ABLK + wave * ROWS_PER_AWAVE;
#pragma unroll
    for (int rr = 0; rr < ROWS_PER_AWAVE; ++rr) {
        const int r      = r0 + rr;
        const int bank   = r >> 11;                 // / (NC*NM)
        const int within = r & (NC * NM - 1);
        const float* src = (bank ? gbank : pbank) + (size_t)within * ND;
        const float4 v = reinterpret_cast<const float4*>(src)[lane];
        float ss = v.x * v.x + v.y * v.y + v.z * v.z + v.w * v.w;
        ss = wave_reduce(ss);
        const float inv = 1.0f / (fmaxf(sqrtf(ss), EPSF) * (float)NM);
        acc.x += v.x * inv; acc.y += v.y * inv;
        acc.z += v.z * inv; acc.w += v.w * inv;
    }

    __shared__ float4 red[4][64];
    red[wave][lane] = acc;
    __syncthreads();
    if (wave == 0) {
        float4 a = red[0][lane], b = red[1][lane];
        float4 c = red[2][lane], d = red[3][lane];
        a.x += b.x + c.x + d.x; a.y += b.y + c.y + d.y;
        a.z += b.z + c.z + d.z; a.w += b.w + c.w + d.w;
        reinterpret_cast<float4*>(partials + (size_t)blk * ND)[lane] = a;
    }
}

// ---- Kernel 2: sum 16 partials per combo -> bankbar (8 blocks) ----
__global__ __launch_bounds__(256) void bank_final_kernel(
    const float* __restrict__ partials, float* __restrict__ bankbar)
{
    const int combo = blockIdx.x;
    const int t     = threadIdx.x;
    float acc = 0.f;
#pragma unroll
    for (int p = 0; p < PART_PER_COMBO; ++p)
        acc += partials[(size_t)(combo * PART_PER_COMBO + p) * ND + t];
    bankbar[(size_t)combo * ND + t] = acc;
}

// ---- Kernel 3: per-sample loss; one atomicAdd(out) per block ----
__global__ __launch_bounds__(256) void loss_kernel(
    const float* __restrict__ hp, const float* __restrict__ hg,
    const int* __restrict__ label, const int* __restrict__ censor,
    const float* __restrict__ bankbar, float* __restrict__ out)
{
    __shared__ float sb[2 * NC * ND];   // 8 KiB
    for (int i = threadIdx.x; i < 2 * NC * ND; i += 256)
        sb[i] = bankbar[i];
    __syncthreads();

    const int wave = threadIdx.x >> 6;
    const int lane = threadIdx.x & 63;
    const int wid  = blockIdx.x * 4 + wave;

    float contrib = 0.0f;
#pragma unroll
    for (int i = 0; i < SPW; ++i) {
        const int b = wid * SPW + i;
        const float4 vp = reinterpret_cast<const float4*>(hp + (size_t)b * ND)[lane];
        const float4 vg = reinterpret_cast<const float4*>(hg + (size_t)b * ND)[lane];
        const int  l   = label[b];
        const bool evt = (censor[b] == 0);

        float s0p = vp.x * vp.x + vp.y * vp.y + vp.z * vp.z + vp.w * vp.w;
        float s0g = vg.x * vg.x + vg.y * vg.y + vg.z * vg.z + vg.w * vg.w;
        float scp[NC], scg[NC];
#pragma unroll
        for (int c = 0; c < NC; ++c) {
            const float4 wp4 = reinterpret_cast<const float4*>(sb + c * ND)[lane];
            const float4 wg4 = reinterpret_cast<const float4*>(sb + (NC + c) * ND)[lane];
            scp[c] = vp.x * wp4.x + vp.y * wp4.y + vp.z * wp4.z + vp.w * wp4.w;
            scg[c] = vg.x * wg4.x + vg.y * wg4.y + vg.z * wg4.z + vg.w * wg4.w;
        }
#pragma unroll
        for (int off = 32; off >= 1; off >>= 1) {
            s0p += __shfl_xor(s0p, off, 64);
            s0g += __shfl_xor(s0g, off, 64);
#pragma unroll
            for (int c = 0; c < NC; ++c) {
                scp[c] += __shfl_xor(scp[c], off, 64);
                scg[c] += __shfl_xor(scg[c], off, 64);
            }
        }
        const float invp = 1.0f / fmaxf(sqrtf(s0p), EPSF);
        const float invg = 1.0f / fmaxf(sqrtf(s0g), EPSF);

#pragma unroll
        for (int md = 0; md < 2; ++md) {
            const float inv = md ? invg : invp;
            float sum = 0.f, cml = 0.f, sge = 0.f, slt = 0.f;
#pragma unroll
            for (int c = 0; c < NC; ++c) {
                const float x = (md ? scg[c] : scp[c]) * inv;
                sum += x;
                if (c == l) cml = x;
                if (c >= l) sge += x; else slt += x;
            }
            float pos, neg;
            if (evt) {
                pos = cml;
                neg = (sum - cml) * (1.0f / (NC - 1));
            } else {
                pos = sge / (float)(NC - l);          // l==0 -> pos_all
                neg = slt / (float)(l > 0 ? l : 1);   // l==0 -> 0
            }
            contrib += neg - pos;
        }
    }

    __shared__ float wpart[4];
    if (lane == 0) wpart[wave] = contrib;
    __syncthreads();
    if (threadIdx.x == 0)
        atomicAdd(out, wpart[0] + wpart[1] + wpart[2] + wpart[3]);
}

extern "C" void kernel_launch(void* const* d_in, const int* in_sizes, int n_in,
                              void* d_out, int out_size, void* d_ws, size_t ws_size,
                              hipStream_t stream)
{
    const float* hp     = (const float*)d_in[0];
    const float* hg     = (const float*)d_in[1];
    const float* pb     = (const float*)d_in[2];
    const float* gb     = (const float*)d_in[3];
    const int*   label  = (const int*)d_in[4];
    const int*   censor = (const int*)d_in[5];
    float*       out    = (float*)d_out;

    float* partials = (float*)d_ws;                           // ABLK*ND = 128 KiB
    float* bankbar  = partials + (size_t)ABLK * ND;           // 8 KiB

    bank_partial_kernel<<<ABLK, 256, 0, stream>>>(pb, gb, partials, out);
    bank_final_kernel  <<<2 * NC, 256, 0, stream>>>(partials, bankbar);
    loss_kernel        <<<BBLK, 256, 0, stream>>>(hp, hg, label, censor,
                                                  bankbar, out);
}

// Round 7
// 30.648 us; speedup vs baseline: 9.0720x; 1.4177x over previous
//
#include <hip/hip_runtime.h>

// ProSurv similarity loss, collapsed:
//   cm[b,c] = (h[b] . bankbar[c]) / max(||h[b]||, eps)
//   bankbar[c] = (1/M) sum_m bank[c,m] / max(||bank[c,m]||, eps)
// 3 dispatches, no memsets, d_out written by exactly one plain store:
//   1) bank_kernel: 64 blocks, partials + last-block finalize (modulo
//      counter -> works with ANY initial counter value, incl. 0xAA poison;
//      64 | 2^32 so replay wraparound keeps residues).
//   2) loss_kernel: 512 blocks x 4 waves x 8 samples, lpart plain stores.
//   3) final_kernel: 1 block sums lpart -> out[0].

constexpr int NC = 4;     // classes
constexpr int NM = 512;   // prototypes per class
constexpr int ND = 256;   // feature dim
constexpr float EPSF = 1e-12f;

constexpr int ABLK = 64;                              // bank_kernel blocks (POW2!)
constexpr int ROWS_PER_ABLK  = 2 * NC * NM / ABLK;    // 64
constexpr int ROWS_PER_AWAVE = ROWS_PER_ABLK / 4;     // 16
constexpr int PART_PER_COMBO = ABLK / (2 * NC);       // 8

constexpr int BBLK = 512;                             // loss blocks
constexpr int SPW  = 8;                               // samples per wave

__device__ __forceinline__ float wave_reduce(float v) {
#pragma unroll
    for (int off = 32; off >= 1; off >>= 1)
        v += __shfl_xor(v, off, 64);
    return v;
}

// ---- Kernel 1: bank partials + last-block finalize -> bankbar ----
__global__ __launch_bounds__(256) void bank_kernel(
    const float* __restrict__ pbank, const float* __restrict__ gbank,
    float* __restrict__ partials, float* __restrict__ bankbar,
    unsigned int* __restrict__ counterA)
{
    const int blk  = blockIdx.x;
    const int wave = threadIdx.x >> 6;
    const int lane = threadIdx.x & 63;

    float4 acc = {0.f, 0.f, 0.f, 0.f};
    const int r0 = blk * ROWS_PER_ABLK + wave * ROWS_PER_AWAVE;
#pragma unroll
    for (int rr = 0; rr < ROWS_PER_AWAVE; ++rr) {
        const int r      = r0 + rr;
        const int bank   = r >> 11;                 // / (NC*NM)
        const int within = r & (NC * NM - 1);
        const float* src = (bank ? gbank : pbank) + (size_t)within * ND;
        const float4 v = reinterpret_cast<const float4*>(src)[lane];
        float ss = v.x * v.x + v.y * v.y + v.z * v.z + v.w * v.w;
        ss = wave_reduce(ss);
        const float inv = 1.0f / (fmaxf(sqrtf(ss), EPSF) * (float)NM);
        acc.x += v.x * inv; acc.y += v.y * inv;
        acc.z += v.z * inv; acc.w += v.w * inv;
    }

    __shared__ float4 red[4][64];
    red[wave][lane] = acc;
    __syncthreads();
    if (wave == 0) {
        float4 a = red[0][lane], b = red[1][lane];
        float4 c = red[2][lane], d = red[3][lane];
        a.x += b.x + c.x + d.x; a.y += b.y + c.y + d.y;
        a.z += b.z + c.z + d.z; a.w += b.w + c.w + d.w;
        reinterpret_cast<float4*>(partials + (size_t)blk * ND)[lane] = a;
    }
    __syncthreads();   // compiler drains vmcnt before barrier

    __shared__ bool last;
    if (threadIdx.x == 0) {
        __threadfence();                              // release partials
        const unsigned int old = atomicAdd(counterA, 1u);
        last = ((old & (ABLK - 1)) == ABLK - 1);      // counter never reset
    }
    __syncthreads();

    if (last) {
        __threadfence();                              // acquire all partials
        const int c = threadIdx.x >> 5;               // combo 0..7
        const int j = threadIdx.x & 31;
#pragma unroll
        for (int k = 0; k < 2; ++k) {
            const int f4 = j + k * 32;                // float4 col 0..63
            float4 s = {0.f, 0.f, 0.f, 0.f};
#pragma unroll
            for (int p = 0; p < PART_PER_COMBO; ++p) {
                const float4 v = reinterpret_cast<const float4*>(
                    partials + (size_t)(c * PART_PER_COMBO + p) * ND)[f4];
                s.x += v.x; s.y += v.y; s.z += v.z; s.w += v.w;
            }
            reinterpret_cast<float4*>(bankbar + (size_t)c * ND)[f4] = s;
        }
    }
}

// ---- Kernel 2: per-sample loss; plain lpart store per block ----
__global__ __launch_bounds__(256) void loss_kernel(
    const float* __restrict__ hp, const float* __restrict__ hg,
    const int* __restrict__ label, const int* __restrict__ censor,
    const float* __restrict__ bankbar, float* __restrict__ lpart)
{
    __shared__ float sb[2 * NC * ND];   // 8 KiB
    for (int i = threadIdx.x; i < 2 * NC * ND; i += 256)
        sb[i] = bankbar[i];
    __syncthreads();

    const int wave = threadIdx.x >> 6;
    const int lane = threadIdx.x & 63;
    const int wid  = blockIdx.x * 4 + wave;

    float contrib = 0.0f;
    for (int i = 0; i < SPW; ++i) {
        const int b = wid * SPW + i;
        const float4 vp = reinterpret_cast<const float4*>(hp + (size_t)b * ND)[lane];
        const float4 vg = reinterpret_cast<const float4*>(hg + (size_t)b * ND)[lane];
        const int  l   = label[b];
        const bool evt = (censor[b] == 0);

        float s0p = vp.x * vp.x + vp.y * vp.y + vp.z * vp.z + vp.w * vp.w;
        float s0g = vg.x * vg.x + vg.y * vg.y + vg.z * vg.z + vg.w * vg.w;
        float scp[NC], scg[NC];
#pragma unroll
        for (int c = 0; c < NC; ++c) {
            const float4 wp4 = reinterpret_cast<const float4*>(sb + c * ND)[lane];
            const float4 wg4 = reinterpret_cast<const float4*>(sb + (NC + c) * ND)[lane];
            scp[c] = vp.x * wp4.x + vp.y * wp4.y + vp.z * wp4.z + vp.w * wp4.w;
            scg[c] = vg.x * wg4.x + vg.y * wg4.y + vg.z * wg4.z + vg.w * wg4.w;
        }
#pragma unroll
        for (int off = 32; off >= 1; off >>= 1) {
            s0p += __shfl_xor(s0p, off, 64);
            s0g += __shfl_xor(s0g, off, 64);
#pragma unroll
            for (int c = 0; c < NC; ++c) {
                scp[c] += __shfl_xor(scp[c], off, 64);
                scg[c] += __shfl_xor(scg[c], off, 64);
            }
        }
        const float invp = 1.0f / fmaxf(sqrtf(s0p), EPSF);
        const float invg = 1.0f / fmaxf(sqrtf(s0g), EPSF);

#pragma unroll
        for (int md = 0; md < 2; ++md) {
            const float inv = md ? invg : invp;
            float sum = 0.f, cml = 0.f, sge = 0.f, slt = 0.f;
#pragma unroll
            for (int c = 0; c < NC; ++c) {
                const float x = (md ? scg[c] : scp[c]) * inv;
                sum += x;
                if (c == l) cml = x;
                if (c >= l) sge += x; else slt += x;
            }
            float pos, neg;
            if (evt) {
                pos = cml;
                neg = (sum - cml) * (1.0f / (NC - 1));
            } else {
                pos = sge / (float)(NC - l);          // l==0 -> pos_all
                neg = slt / (float)(l > 0 ? l : 1);   // l==0 -> 0
            }
            contrib += neg - pos;
        }
    }

    __shared__ float wpart[4];
    if (lane == 0) wpart[wave] = contrib;
    __syncthreads();
    if (threadIdx.x == 0)
        lpart[blockIdx.x] = wpart[0] + wpart[1] + wpart[2] + wpart[3];
}

// ---- Kernel 3: one block sums BBLK partials -> out[0] ----
__global__ __launch_bounds__(256) void final_kernel(
    const float* __restrict__ lpart, float* __restrict__ out)
{
    const int t = threadIdx.x;
    float v = lpart[t] + lpart[t + 256];
    v = wave_reduce(v);
    __shared__ float wp[4];
    if ((t & 63) == 0) wp[t >> 6] = v;
    __syncthreads();
    if (t == 0) out[0] = wp[0] + wp[1] + wp[2] + wp[3];
}

extern "C" void kernel_launch(void* const* d_in, const int* in_sizes, int n_in,
                              void* d_out, int out_size, void* d_ws, size_t ws_size,
                              hipStream_t stream)
{
    const float* hp     = (const float*)d_in[0];
    const float* hg     = (const float*)d_in[1];
    const float* pb     = (const float*)d_in[2];
    const float* gb     = (const float*)d_in[3];
    const int*   label  = (const int*)d_in[4];
    const int*   censor = (const int*)d_in[5];
    float*       out    = (float*)d_out;

    unsigned int* counterA = (unsigned int*)d_ws;             // never reset (modulo)
    float* partials = (float*)((char*)d_ws + 256);            // ABLK*ND = 64 KiB
    float* bankbar  = partials + (size_t)ABLK * ND;           // 8 KiB
    float* lpart    = bankbar + 2 * NC * ND;                  // BBLK floats

    bank_kernel <<<ABLK, 256, 0, stream>>>(pb, gb, partials, bankbar, counterA);
    loss_kernel <<<BBLK, 256, 0, stream>>>(hp, hg, label, censor, bankbar, lpart);
    final_kernel<<<1,    256, 0, stream>>>(lpart, out);
}

// Round 8
// 20.925 us; speedup vs baseline: 13.2870x; 1.4646x over previous
//
#include <hip/hip_runtime.h>

// ProSurv similarity loss, collapsed:
//   cm[b,c] = (h[b] . bankbar[c]) / max(||h[b]||, eps)
//   bankbar[c] = (1/M) sum_m bank[c,m] / max(||bank[c,m]||, eps)
// 3 dispatches, no memsets:
//   1) bank_kernel: 64 blocks, partials + last-block finalize (modulo counter,
//      poison-proof, wraparound-safe).
//   2) loss_kernel: 512 blocks x 256 thr; 8 threads per sample, LDS-staged
//      rows (chunk-padded, bank-conflict-free), per-thread FMA dots,
//      3-step shfl finish. No atomics, plain lpart store.
//   3) final_kernel: 1 block sums lpart -> out[0] (single d_out store).

constexpr int NC = 4;     // classes
constexpr int NM = 512;   // prototypes per class
constexpr int ND = 256;   // feature dim
constexpr float EPSF = 1e-12f;

constexpr int ABLK = 64;                              // bank_kernel blocks (pow2)
constexpr int ROWS_PER_ABLK  = 2 * NC * NM / ABLK;    // 64
constexpr int ROWS_PER_AWAVE = ROWS_PER_ABLK / 4;     // 16
constexpr int PART_PER_COMBO = ABLK / (2 * NC);       // 8

constexpr int BBLK = 512;                             // loss blocks
constexpr int SPB  = 32;                              // samples per loss block
constexpr int CHW  = 36;                              // padded chunk width (32+4)
constexpr int SROW = 8 * CHW;                         // 288 floats per padded row

__device__ __forceinline__ float wave_reduce(float v) {
#pragma unroll
    for (int off = 32; off >= 1; off >>= 1)
        v += __shfl_xor(v, off, 64);
    return v;
}

// ---- Kernel 1: bank partials + last-block finalize -> bankbar ----
__global__ __launch_bounds__(256) void bank_kernel(
    const float* __restrict__ pbank, const float* __restrict__ gbank,
    float* __restrict__ partials, float* __restrict__ bankbar,
    unsigned int* __restrict__ counterA)
{
    const int blk  = blockIdx.x;
    const int wave = threadIdx.x >> 6;
    const int lane = threadIdx.x & 63;

    float4 acc = {0.f, 0.f, 0.f, 0.f};
    const int r0 = blk * ROWS_PER_ABLK + wave * ROWS_PER_AWAVE;
#pragma unroll
    for (int rr = 0; rr < ROWS_PER_AWAVE; ++rr) {
        const int r      = r0 + rr;
        const int bank   = r >> 11;
        const int within = r & (NC * NM - 1);
        const float* src = (bank ? gbank : pbank) + (size_t)within * ND;
        const float4 v = reinterpret_cast<const float4*>(src)[lane];
        float ss = v.x * v.x + v.y * v.y + v.z * v.z + v.w * v.w;
        ss = wave_reduce(ss);
        const float inv = 1.0f / (fmaxf(sqrtf(ss), EPSF) * (float)NM);
        acc.x += v.x * inv; acc.y += v.y * inv;
        acc.z += v.z * inv; acc.w += v.w * inv;
    }

    __shared__ float4 red[4][64];
    red[wave][lane] = acc;
    __syncthreads();
    if (wave == 0) {
        float4 a = red[0][lane], b = red[1][lane];
        float4 c = red[2][lane], d = red[3][lane];
        a.x += b.x + c.x + d.x; a.y += b.y + c.y + d.y;
        a.z += b.z + c.z + d.z; a.w += b.w + c.w + d.w;
        reinterpret_cast<float4*>(partials + (size_t)blk * ND)[lane] = a;
    }
    __syncthreads();

    __shared__ bool last;
    if (threadIdx.x == 0) {
        __threadfence();                              // release partials
        const unsigned int old = atomicAdd(counterA, 1u);
        last = ((old & (ABLK - 1)) == ABLK - 1);      // counter never reset
    }
    __syncthreads();

    if (last) {
        __threadfence();                              // acquire all partials
        const int c = threadIdx.x >> 5;               // combo 0..7
        const int j = threadIdx.x & 31;
#pragma unroll
        for (int k = 0; k < 2; ++k) {
            const int f4 = j + k * 32;
            float4 s = {0.f, 0.f, 0.f, 0.f};
#pragma unroll
            for (int p = 0; p < PART_PER_COMBO; ++p) {
                const float4 v = reinterpret_cast<const float4*>(
                    partials + (size_t)(c * PART_PER_COMBO + p) * ND)[f4];
                s.x += v.x; s.y += v.y; s.z += v.z; s.w += v.w;
            }
            reinterpret_cast<float4*>(bankbar + (size_t)c * ND)[f4] = s;
        }
    }
}

// ---- Kernel 2: loss, 8 threads/sample, LDS-staged ----
__global__ __launch_bounds__(256) void loss_kernel(
    const float* __restrict__ hp, const float* __restrict__ hg,
    const int* __restrict__ label, const int* __restrict__ censor,
    const float* __restrict__ bankbar, float* __restrict__ lpart)
{
    __shared__ __align__(16) float hbuf[SPB * SROW];   // 36 KiB, reused per modality
    __shared__ __align__(16) float bb[8 * SROW];       // 9 KiB padded bankbar

    const int t = threadIdx.x;
    const int s = t >> 3;          // sample slot 0..31
    const int k = t & 7;           // dim-chunk 0..7 (32 dims each)
    const int sg = blockIdx.x * SPB + s;     // global sample

    // stage padded bankbar: 512 float4s, 2 per thread
#pragma unroll
    for (int it = 0; it < 2; ++it) {
        const int f4    = t + it * 256;
        const int combo = f4 >> 6;
        const int rem   = f4 & 63;
        const float4 v  = reinterpret_cast<const float4*>(bankbar)[f4];
        *reinterpret_cast<float4*>(&bb[combo * SROW + (rem >> 3) * CHW + (rem & 7) * 4]) = v;
    }

    const int l   = label[sg];
    const bool evt = (censor[sg] == 0);

    float s0[2], sc[2][NC];

#pragma unroll
    for (int md = 0; md < 2; ++md) {
        // stage 32 rows (32 KB) coalesced -> padded LDS
        const float* src = (md ? hg : hp) + (size_t)blockIdx.x * SPB * ND;
        __syncthreads();   // protect hbuf from previous modality's readers
#pragma unroll
        for (int it = 0; it < 8; ++it) {
            const int f4  = t + it * 256;           // 0..2047
            const int ss  = f4 >> 6;                // sample slot
            const int rem = f4 & 63;
            const float4 v = reinterpret_cast<const float4*>(src)[f4];
            *reinterpret_cast<float4*>(&hbuf[ss * SROW + (rem >> 3) * CHW + (rem & 7) * 4]) = v;
        }
        __syncthreads();

        // per-thread: own 32-dim chunk of own sample
        const float* hrow = &hbuf[s * SROW + k * CHW];
        float4 hx[8];
#pragma unroll
        for (int j = 0; j < 8; ++j)
            hx[j] = reinterpret_cast<const float4*>(hrow)[j];

        float a0 = 0.f;
#pragma unroll
        for (int j = 0; j < 8; ++j)
            a0 += hx[j].x * hx[j].x + hx[j].y * hx[j].y
                + hx[j].z * hx[j].z + hx[j].w * hx[j].w;

        float ac[NC];
#pragma unroll
        for (int c = 0; c < NC; ++c) {
            const float* brow = &bb[(md * NC + c) * SROW + k * CHW];
            float acc = 0.f;
#pragma unroll
            for (int j = 0; j < 8; ++j) {
                const float4 w = reinterpret_cast<const float4*>(brow)[j];
                acc += hx[j].x * w.x + hx[j].y * w.y
                     + hx[j].z * w.z + hx[j].w * w.w;
            }
            ac[c] = acc;
        }

        // 3-step butterfly over the 8-lane group (all lanes get totals)
#pragma unroll
        for (int off = 1; off <= 4; off <<= 1) {
            a0 += __shfl_xor(a0, off, 64);
#pragma unroll
            for (int c = 0; c < NC; ++c)
                ac[c] += __shfl_xor(ac[c], off, 64);
        }
        s0[md] = a0;
#pragma unroll
        for (int c = 0; c < NC; ++c) sc[md][c] = ac[c];
    }

    // per-thread loss (group-replicated; only k==0 contributes)
    float contrib = 0.0f;
#pragma unroll
    for (int md = 0; md < 2; ++md) {
        const float inv = 1.0f / fmaxf(sqrtf(s0[md]), EPSF);
        float sum = 0.f, cml = 0.f, sge = 0.f, slt = 0.f;
#pragma unroll
        for (int c = 0; c < NC; ++c) {
            const float x = sc[md][c] * inv;
            sum += x;
            if (c == l) cml = x;
            if (c >= l) sge += x; else slt += x;
        }
        float pos, neg;
        if (evt) {
            pos = cml;
            neg = (sum - cml) * (1.0f / (NC - 1));
        } else {
            pos = sge / (float)(NC - l);          // l==0 -> pos_all
            neg = slt / (float)(l > 0 ? l : 1);   // l==0 -> 0
        }
        contrib += neg - pos;
    }
    if (k != 0) contrib = 0.0f;

    // block reduction -> lpart
    contrib = wave_reduce(contrib);
    __shared__ float wpart[4];
    if ((t & 63) == 0) wpart[t >> 6] = contrib;
    __syncthreads();
    if (t == 0)
        lpart[blockIdx.x] = wpart[0] + wpart[1] + wpart[2] + wpart[3];
}

// ---- Kernel 3: one block sums BBLK partials -> out[0] ----
__global__ __launch_bounds__(256) void final_kernel(
    const float* __restrict__ lpart, float* __restrict__ out)
{
    const int t = threadIdx.x;
    float v = lpart[t] + lpart[t + 256];
    v = wave_reduce(v);
    __shared__ float wp[4];
    if ((t & 63) == 0) wp[t >> 6] = v;
    __syncthreads();
    if (t == 0) out[0] = wp[0] + wp[1] + wp[2] + wp[3];
}

extern "C" void kernel_launch(void* const* d_in, const int* in_sizes, int n_in,
                              void* d_out, int out_size, void* d_ws, size_t ws_size,
                              hipStream_t stream)
{
    const float* hp     = (const float*)d_in[0];
    const float* hg     = (const float*)d_in[1];
    const float* pb     = (const float*)d_in[2];
    const float* gb     = (const float*)d_in[3];
    const int*   label  = (const int*)d_in[4];
    const int*   censor = (const int*)d_in[5];
    float*       out    = (float*)d_out;

    unsigned int* counterA = (unsigned int*)d_ws;             // never reset (modulo)
    float* partials = (float*)((char*)d_ws + 256);            // ABLK*ND = 64 KiB
    float* bankbar  = partials + (size_t)ABLK * ND;           // 8 KiB
    float* lpart    = bankbar + 2 * NC * ND;                  // BBLK floats

    bank_kernel <<<ABLK, 256, 0, stream>>>(pb, gb, partials, bankbar, counterA);
    loss_kernel <<<BBLK, 256, 0, stream>>>(hp, hg, label, censor, bankbar, lpart);
    final_kernel<<<1,    256, 0, stream>>>(lpart, out);
}